// Round 22
// baseline (251.732 us; speedup 1.0000x reference)
//
#include <hip/hip_runtime.h>
#include <math.h>

// FlashMultiHeadAttention: B=32 S=500 H=1024 NH=16 HD=64, rope + rel-pos-bias + key-pad mask.
// Pipeline: [gather-list scan w/ inline mask-mode detect]
//           [PREP: W cvt x4 + Q cvt + K/V gather-cvt + rope table, ONE launch]
//           [FUSED proj GEMM: Q(full, rope+transpose) + K(compact -> roped swizzled Ktg tiles)
//            + V(compact -> transposed swizzled Vtg tiles), ONE launch]
//           [flash attn: P redistributed in-register via ds_bpermute (no P LDS buffer)]
//           [out proj GEMM]
// GEMM core: 256x128 tile, BK=32, 2 LDS buffers (48KB -> 3 blocks/CU co-resident),
// row-pair packed 128B LDS rows + XOR slot swizzle, T3-minimum single-barrier loop.

typedef unsigned short u16;
typedef unsigned int   u32;
typedef unsigned char  u8;
using bf16x8 = __attribute__((ext_vector_type(8))) short;
using f32x4  = __attribute__((ext_vector_type(4))) float;
using f32x2  = __attribute__((ext_vector_type(2))) float;
using u16x4  = __attribute__((ext_vector_type(4))) unsigned short;

#define DEV __device__ __forceinline__

#if __has_builtin(__builtin_amdgcn_exp2f)
#define EXP2(x) __builtin_amdgcn_exp2f(x)
#else
#define EXP2(x) exp2f(x)
#endif

DEV u16 f2bf(float f) {                 // RNE f32 -> bf16
  union { float f; u32 u; } c; c.f = f;
  u32 u = c.u;
  return (u16)((u + 0x7FFFu + ((u >> 16) & 1u)) >> 16);
}
DEV float bf2f(u16 h) {
  union { u32 u; float f; } c; c.u = ((u32)h) << 16;
  return c.f;
}
DEV u32 cvtpk(float a, float b) {       // packed pair via HW cvt (T12)
  u32 r;
  asm("v_cvt_pk_bf16_f32 %0, %1, %2" : "=v"(r) : "v"(a), "v"(b));
  return r;
}

// async global->LDS, 16B/lane; LDS dest = wave-uniform base + lane*16 (linear).
DEV void async16(void* l, const void* g) {
  __builtin_amdgcn_global_load_lds(
      (__attribute__((address_space(1))) unsigned int*)g,
      (__attribute__((address_space(3))) unsigned int*)l, 16, 0, 0);
}

// ---------------- gather list + inline mask-mode detection ----------------
__global__ __launch_bounds__(512) void build_gather(const void* __restrict__ mraw,
                                                    u16* __restrict__ karr,
                                                    int* __restrict__ kept) {
  const int b = blockIdx.x;
  const int t = threadIdx.x;
  const int lane = t & 63, wave = t >> 6;
  __shared__ int s_li, s_lf;
  __shared__ int wbase[8];
  __shared__ int wpop[8];
  if (t == 0) { s_li = 0; s_lf = 0; }
  __syncthreads();
  const u32* w = (const u32*)mraw;
  int li = 0, lf = 0;
  for (int g = t; g < 4000; g += 512) {      // same 4000 words in every block -> same mode
    u32 v = w[g];
    li |= !(v == 0u || v == 1u);
    lf |= !(v == 0u || v == 0x3F800000u);
  }
  if (li) atomicOr(&s_li, 1);
  if (lf) atomicOr(&s_lf, 1);
  __syncthreads();
  const int mode = (!s_li) ? 0 : ((!s_lf) ? 1 : 2);   // 0=int32, 1=float32, 2=uint8
  int v = 0;
  if (t < 500) {
    if (mode == 0)      v = ((const int*)mraw)[b * 500 + t] != 0;
    else if (mode == 1) v = (((const float*)mraw)[b * 500 + t] != 0.0f);
    else                v = ((const u8*)mraw)[b * 500 + t] != 0;
  }
  unsigned long long bal = __ballot(v != 0);
  karr[b * 512 + t] = 0xFFFF;
  if (lane == 0) wpop[wave] = __popcll(bal);
  __syncthreads();
  if (t == 0) {
    int s = 0;
    for (int ww = 0; ww < 8; ++ww) { wbase[ww] = s; s += wpop[ww]; }
    kept[b] = s;
  }
  __syncthreads();
  if (v) {
    int rank = wbase[wave] + __popcll(bal & ((1ull << lane) - 1ull));
    karr[b * 512 + rank] = (u16)t;
  }
}

// ---------------- PREP: W cvt x4 | Q cvt | K/V gather-cvt | rope table (one launch) ----------
// grid 36543 = 4096 (W) + 16000 (Q) + 16384 (K/V gather) + 63 (rope table)
__global__ __launch_bounds__(256) void prep(
    const float* __restrict__ Wq, const float* __restrict__ Wk,
    const float* __restrict__ Wv, const float* __restrict__ Wo,
    u16* __restrict__ Wb,
    const float* __restrict__ query, u16* __restrict__ Xq,
    const float* __restrict__ key_, const float* __restrict__ value,
    const u16* __restrict__ karr, const int* __restrict__ kept,
    u16* __restrict__ XkC, u16* __restrict__ XvC,
    float* __restrict__ tab) {
  const int bid = blockIdx.x;
  const int tid = threadIdx.x;
  if (bid < 4096) {
    const int wsel = bid >> 10;
    const float* src = (wsel == 0) ? Wq : (wsel == 1) ? Wk : (wsel == 2) ? Wv : Wo;
    int i = (bid & 1023) * 256 + tid;
    f32x4 f = *(const f32x4*)(src + (size_t)i * 4);
    u16x4 o;
    o[0] = f2bf(f[0]); o[1] = f2bf(f[1]); o[2] = f2bf(f[2]); o[3] = f2bf(f[3]);
    *(u16x4*)(Wb + (size_t)wsel * 1048576 + (size_t)i * 4) = o;
  } else if (bid < 20096) {
    int i = (bid - 4096) * 256 + tid;
    f32x4 f = *(const f32x4*)(query + (size_t)i * 4);
    u16x4 o;
    o[0] = f2bf(f[0]); o[1] = f2bf(f[1]); o[2] = f2bf(f[2]); o[3] = f2bf(f[3]);
    *(u16x4*)(Xq + (size_t)i * 4) = o;
  } else if (bid < 36480) {
    const int local = bid - 20096;
    const int z = local >> 13;                       // 0 = K, 1 = V
    const int rem = local & 8191;
    const int b = rem >> 8;
    const int r = (rem & 255) * 2 + (tid >> 7);
    if (r >= kept[b]) return;
    const float* src = z ? value : key_;
    u16* dst = z ? XvC : XkC;
    const int c = (tid & 127) * 8;
    const int tok = karr[b * 512 + r];
    const float* s = src + ((size_t)b * 500 + tok) * 1024 + c;
    f32x4 f0 = *(const f32x4*)s;
    f32x4 f1 = *(const f32x4*)(s + 4);
    u16 o[8];
    o[0] = f2bf(f0[0]); o[1] = f2bf(f0[1]); o[2] = f2bf(f0[2]); o[3] = f2bf(f0[3]);
    o[4] = f2bf(f1[0]); o[5] = f2bf(f1[1]); o[6] = f2bf(f1[2]); o[7] = f2bf(f1[3]);
    *(bf16x8*)(dst + ((size_t)b * 512 + r) * 1024 + c) = *(bf16x8*)o;
  } else {
    int idx = (bid - 36480) * 256 + tid;
    if (idx >= 16000) return;
    int s = idx >> 5, j = idx & 31;
    float ang = (float)s * exp2f(-(float)j * 0.41524100f);  // 10000^(-j/32)
    float sn, cs;
    sincosf(ang, &sn, &cs);
    tab[idx * 2] = cs;
    tab[idx * 2 + 1] = sn;
  }
}

// ---------------- shared GEMM core (round-14 proven) ----------------
// 256x128 tile, BK=32, 512 thr / 8 waves (4Mx2N), per-wave 64x64 (4x4 frags).
// 2 LDS buffers (A 16KB + B 8KB each). Row-pair packed 128B rows, XOR slot swizzle.
// T3-minimum loop: STAGE(t+1,buf^1) -> ds_read -> lgkm(0) -> 16 MFMA -> vmcnt(0) -> barrier.
DEV void gemm_core(const u16* __restrict__ A, size_t abase,
                   const u16* __restrict__ W,
                   int m0, int n0, int Mloc,
                   u16* AS, u16* BS, f32x4 (&acc)[4][4], int tid) {
  const int wave = tid >> 6;
  const int wr = wave >> 1, wc = wave & 1;            // 4M x 2N
  const int fr = tid & 15, fo = (tid >> 4) & 3;
  const int fr2 = fr >> 1;
  const int aslot = ((4 * (fr & 1) + fo) ^ fr2) * 8;  // u16 offset within 64-u16 LDS row
  const int ATILE = 128 * 64;                         // 16KB
  const int BTILE = 64 * 64;                          // 8KB

#pragma unroll
  for (int mi = 0; mi < 4; ++mi)
#pragma unroll
    for (int ni = 0; ni < 4; ++ni)
#pragma unroll
      for (int j = 0; j < 4; ++j) acc[mi][ni][j] = 0.f;

  auto STG = [&](int t, int buf) {
    u16* sA = &AS[buf * ATILE];
    u16* sB = &BS[buf * BTILE];
#pragma unroll
    for (int i = 0; i < 2; ++i) {                     // A: 1024 chunks
      int c = i * 512 + tid;
      int r = c >> 3, v = (c & 7) ^ (r & 7);
      int ar = min(m0 + 2 * r + (v >> 2), Mloc - 1);
      async16(&sA[c * 8], A + abase + (size_t)ar * 1024 + t * 32 + (v & 3) * 8);
    }
    {                                                 // B: 512 chunks
      int c = tid;
      int r = c >> 3, v = (c & 7) ^ (r & 7);
      int nr = n0 + 2 * r + (v >> 2);
      async16(&sB[c * 8], W + (size_t)nr * 1024 + t * 32 + (v & 3) * 8);
    }
  };

  STG(0, 0);
  asm volatile("s_waitcnt vmcnt(0)" ::: "memory");
  __builtin_amdgcn_sched_barrier(0);
  __builtin_amdgcn_s_barrier();

  int cur = 0;
  for (int t = 0; t < 32; ++t) {
    if (t + 1 < 32) STG(t + 1, cur ^ 1);
    const u16* a0 = &AS[cur * ATILE];
    const u16* b0 = &BS[cur * BTILE];
    bf16x8 a[4], b[4];
#pragma unroll
    for (int mi = 0; mi < 4; ++mi)
      a[mi] = *(const bf16x8*)&a0[(wr * 32 + mi * 8 + fr2) * 64 + aslot];
#pragma unroll
    for (int ni = 0; ni < 4; ++ni)
      b[ni] = *(const bf16x8*)&b0[(wc * 32 + ni * 8 + fr2) * 64 + aslot];
    asm volatile("s_waitcnt lgkmcnt(0)" ::: "memory");
    __builtin_amdgcn_sched_barrier(0);
    __builtin_amdgcn_s_setprio(1);
#pragma unroll
    for (int mi = 0; mi < 4; ++mi)
#pragma unroll
      for (int ni = 0; ni < 4; ++ni)
        acc[mi][ni] = __builtin_amdgcn_mfma_f32_16x16x32_bf16(a[mi], b[ni], acc[mi][ni], 0, 0, 0);
    __builtin_amdgcn_s_setprio(0);
    asm volatile("s_waitcnt vmcnt(0)" ::: "memory");
    __builtin_amdgcn_sched_barrier(0);
    __builtin_amdgcn_s_barrier();
    cur ^= 1;
  }
  __syncthreads();
}

// ---------------- FUSED projection GEMM ----------------
// grid 1528 = 504 (Q full: rope+transpose -> Qro) + 512 (K compact: rope -> swizzled Ktg
// tiles) + 512 (V compact: transpose -> swizzled Vtg tiles).
__global__ __launch_bounds__(512, 4) void gemm_fused(
    const u16* __restrict__ Xq, const u16* __restrict__ XkC, const u16* __restrict__ XvC,
    const u16* __restrict__ Wb,
    const float* __restrict__ bq, const float* __restrict__ bk, const float* __restrict__ bv,
    u16* __restrict__ Qro, u16* __restrict__ Ktg, u16* __restrict__ Vtg,
    const float* __restrict__ tabg, const u16* __restrict__ karr,
    const int* __restrict__ keptp) {
  __shared__ __attribute__((aligned(16))) u16 SH[2 * 128 * 64 + 2 * 64 * 64];  // 48KB
  u16* AS = &SH[0];
  u16* BS = &SH[2 * 128 * 64];
  const int bid = blockIdx.x;
  const int tid = threadIdx.x;
  const int wave = tid >> 6;
  const int wr = wave >> 1, wc = wave & 1;
  const int fr = tid & 15, fo = (tid >> 4) & 3;
  const int lane = tid & 63;

  f32x4 acc[4][4];

  if (bid < 504) {
    // ---- Q path: full M=16000, rope+transpose epilogue -> Qro [bh][s][64] ----
    const int swz = (bid & 7) * 63 + (bid >> 3);
    const int m0 = (swz >> 3) * 256;
    const int n0 = (swz & 7) * 128;
    gemm_core(Xq, 0, Wb, m0, n0, 16000, AS, BS, acc, tid);

    float* fw = (float*)&SH[0] + wave * 1024;         // 4KB per wave (disjoint regions)
    const int hh = (n0 >> 6) + wc;
    const int row = lane >> 2;
    const int jb = (lane & 3) * 8;
    float bvv[4];
#pragma unroll
    for (int ni = 0; ni < 4; ++ni) bvv[ni] = bq[n0 + wc * 64 + ni * 16 + fr];
#pragma unroll
    for (int mi = 0; mi < 4; ++mi) {
#pragma unroll
      for (int ni = 0; ni < 4; ++ni)
#pragma unroll
        for (int r = 0; r < 4; ++r)
          fw[(fo * 4 + r) * 64 + ni * 16 + fr] = acc[mi][ni][r] + bvv[ni];
      int m = m0 + wr * 64 + mi * 16 + row;
      if (m < 16000) {
        int bb = (u32)m / 500u;
        int ss = m - bb * 500;
        u16* dst = Qro + (((size_t)(bb * 16 + hh)) * 500 + ss) * 64;
        bf16x8 va, vb;
#pragma unroll
        for (int p = 0; p < 8; ++p) {
          int j = jb + p;
          float x0 = fw[row * 64 + j];
          float x1 = fw[row * 64 + 32 + j];
          float xe = fw[row * 64 + 2 * j];
          float xo = fw[row * 64 + 2 * j + 1];
          f32x2 cn = *(const f32x2*)(tabg + (ss * 32 + j) * 2);
          va[p] = (short)f2bf(x0 * cn[0] - xo * cn[1]);
          vb[p] = (short)f2bf(x1 * cn[0] + xe * cn[1]);
        }
        *(bf16x8*)(dst + jb) = va;
        *(bf16x8*)(dst + 32 + jb) = vb;
      }
      __builtin_amdgcn_s_waitcnt(0);                  // lgkm: fw reads done before overwrite
    }
  } else {
    // ---- K/V compact paths ----
    const bool isV = (bid >= 1016);
    const int local = isV ? (bid - 1016) : (bid - 504);
    const u16* A = isV ? XvC : XkC;
    const u16* W = Wb + (isV ? 2 : 1) * 1048576;
    const float* bias = isV ? bv : bk;
    const int swz = (local & 7) * 64 + (local >> 3);  // bijective: 512 = 8*64
    const int mb = swz >> 3;
    const int n0 = (swz & 7) * 128;
    const int b = mb >> 1, rb = mb & 1;
    const int kb = keptp[b];
    if (rb * 256 >= kb) return;
    const int m0 = rb * 256;
    gemm_core(A, (size_t)b * 512 * 1024, W, m0, n0, kb, AS, BS, acc, tid);

    // f32 bounce with stride-66 rows (conflict-free strided column reads for V)
    float* fw = (float*)&SH[0] + wave * 1056;         // 16 x 66 f32 per wave (disjoint)
    const int hh = (n0 >> 6) + wc;
    float bvv[4];
#pragma unroll
    for (int ni = 0; ni < 4; ++ni) bvv[ni] = bias[n0 + wc * 64 + ni * 16 + fr];

    if (!isV) {
      // K: rope per rank, write pre-swizzled Ktg tiles [bh][tile][rin][128B]
      const int row = lane >> 2;
      const int jb = (lane & 3) * 8;
#pragma unroll
      for (int mi = 0; mi < 4; ++mi) {
#pragma unroll
        for (int ni = 0; ni < 4; ++ni)
#pragma unroll
          for (int r = 0; r < 4; ++r)
            fw[(fo * 4 + r) * 66 + ni * 16 + fr] = acc[mi][ni][r] + bvv[ni];
        int rk = m0 + wr * 64 + mi * 16 + row;
        int tile = rk >> 6, rin = rk & 63;
        int swk = (rin & 7) << 4;
        if (tile * 64 < kb) {
          char* outp = (char*)(Ktg + (((size_t)(b * 16 + hh)) * 8 + tile) * 4096) + rin * 128;
          bf16x8 va, vb;
          if (rk < kb) {
            int tok = karr[b * 512 + rk];
#pragma unroll
            for (int p = 0; p < 8; ++p) {
              int j = jb + p;
              float x0 = fw[row * 66 + j];
              float x1 = fw[row * 66 + 32 + j];
              float xe = fw[row * 66 + 2 * j];
              float xo = fw[row * 66 + 2 * j + 1];
              f32x2 cn = *(const f32x2*)(tabg + (tok * 32 + j) * 2);
              va[p] = (short)f2bf(x0 * cn[0] - xo * cn[1]);
              vb[p] = (short)f2bf(x1 * cn[0] + xe * cn[1]);
            }
          } else {
#pragma unroll
            for (int p = 0; p < 8; ++p) { va[p] = 0; vb[p] = 0; }
          }
          *(bf16x8*)(outp + ((2 * jb) ^ swk)) = va;
          *(bf16x8*)(outp + ((64 + 2 * jb) ^ swk)) = vb;
        }
        __builtin_amdgcn_s_waitcnt(0);                // lgkm: fw reads done before overwrite
      }
    } else {
      // V: transpose in bounce (lane = d), write pre-swizzled Vtg tiles [bh][tile][d][128B]
      const int d = lane;
      const int swv = (d & 7) << 4;
#pragma unroll
      for (int mi = 0; mi < 4; ++mi) {
#pragma unroll
        for (int ni = 0; ni < 4; ++ni)
#pragma unroll
          for (int r = 0; r < 4; ++r)
            fw[(fo * 4 + r) * 66 + ni * 16 + fr] = acc[mi][ni][r] + bvv[ni];
        int rk0 = m0 + wr * 64 + mi * 16;
        int tile = rk0 >> 6, rin0 = rk0 & 63;
        if (tile * 64 < kb) {
          char* rowp = (char*)(Vtg + (((size_t)(b * 16 + hh)) * 8 + tile) * 4096) + d * 128;
          bf16x8 va, vb;
#pragma unroll
          for (int t2 = 0; t2 < 8; ++t2)
            va[t2] = (rk0 + t2 < kb) ? (short)f2bf(fw[t2 * 66 + d]) : (short)0;
#pragma unroll
          for (int t2 = 0; t2 < 8; ++t2)
            vb[t2] = (rk0 + 8 + t2 < kb) ? (short)f2bf(fw[(8 + t2) * 66 + d]) : (short)0;
          *(bf16x8*)(rowp + ((2 * rin0) ^ swv)) = va;
          *(bf16x8*)(rowp + ((2 * rin0 + 16) ^ swv)) = vb;
        }
        __builtin_amdgcn_s_waitcnt(0);                // lgkm: fw reads done before overwrite
      }
    }
  }
}

// ---------------- out-projection GEMM: full, f32 out ----------------
__global__ __launch_bounds__(512, 4) void gemm_out(const u16* __restrict__ A,
                                                   const u16* __restrict__ W,
                                                   const float* __restrict__ bias,
                                                   float* __restrict__ Cout) {
  __shared__ __attribute__((aligned(16))) u16 SH[2 * 128 * 64 + 2 * 64 * 64];
  u16* AS = &SH[0];
  u16* BS = &SH[2 * 128 * 64];
  const int bid = blockIdx.x;
  const int tid = threadIdx.x;
  const int wave = tid >> 6;
  const int wr = wave >> 1, wc = wave & 1;
  const int fr = tid & 15, fo = (tid >> 4) & 3;
  const int swz = (bid & 7) * 63 + (bid >> 3);
  const int m0 = (swz >> 3) * 256;
  const int n0 = (swz & 7) * 128;

  f32x4 acc[4][4];
  gemm_core(A, 0, W, m0, n0, 16000, AS, BS, acc, tid);

  float* fw = (float*)&SH[0] + wave * 1024;           // 4KB per wave (disjoint regions)
#pragma unroll
  for (int mi = 0; mi < 4; ++mi) {
#pragma unroll
    for (int ni = 0; ni < 4; ++ni) {
      float bv = bias[n0 + wc * 64 + ni * 16 + fr];
#pragma unroll
      for (int r = 0; r < 4; ++r)
        fw[(fo * 4 + r) * 64 + ni * 16 + fr] = acc[mi][ni][r] + bv;
    }
    int lane = tid & 63;
    int ro = lane >> 2, ch = lane & 3;
    int m = m0 + wr * 64 + mi * 16 + ro;
    f32x4 v0 = *(const f32x4*)&fw[ro * 64 + ch * 16];
    f32x4 v1 = *(const f32x4*)&fw[ro * 64 + ch * 16 + 4];
    f32x4 v2 = *(const f32x4*)&fw[ro * 64 + ch * 16 + 8];
    f32x4 v3 = *(const f32x4*)&fw[ro * 64 + ch * 16 + 12];
    if (m < 16000) {
      float* dst = Cout + (size_t)m * 1024 + n0 + wc * 64 + ch * 16;
      *(f32x4*)dst = v0;
      *(f32x4*)(dst + 4) = v1;
      *(f32x4*)(dst + 8) = v2;
      *(f32x4*)(dst + 12) = v3;
    }
    __builtin_amdgcn_s_waitcnt(0);                    // lgkm: fw reads done before overwrite
  }
}

// ---------------- flash attention: compressed k, swapped QK^T, in-reg softmax ----------------
// P redistributed to PV B-fragment layout via 16 ds_bpermute + 8 selects (no P LDS buffer):
// dest lane (fo,fr) pulls cvtpk words of nf=fo>>1 (pa0) / 2+(fo>>1) (pa1) from source lanes
// s0=(fo&1)*32+fr and s1=s0+16.  LDS 52.7KB -> 35.8KB => 4 blocks/CU.
__global__ __launch_bounds__(512) void attn_kernel(const u16* __restrict__ Qr,
                                                   const u16* __restrict__ Ktg,
                                                   const u16* __restrict__ Vtg,
                                                   const float* __restrict__ rel_emb,
                                                   const u16* __restrict__ karr,
                                                   const int* __restrict__ kept,
                                                   u16* __restrict__ AO) {
  const int bid = blockIdx.x;
  const int bh = ((bid >> 5) << 3) | (bid & 7);
  const int qb = (bid >> 3) & 3;
  const int h = bh & 15, b = bh >> 4;
  const int q0 = qb * 128;
  const int tid = threadIdx.x;
  const int wave = tid >> 6;
  const int fr = tid & 15, fo = (tid >> 4) & 3;

  __shared__ __attribute__((aligned(16))) u16 Ks[2][4096];
  __shared__ __attribute__((aligned(16))) u16 Vs[2][4096];
  __shared__ float rel2[640];
  __shared__ u16 okk[512];

  const int nt = (kept[b] + 63) >> 6;
  const float LOG2E = 1.44269504f;
  for (int i = tid; i < 640; i += 512) {
    int g = min(max(q0 - 12 + i, 0), 998);
    rel2[i] = (i == 0) ? -1e30f : rel_emb[g * 16 + h] * LOG2E;   // rel2[0] = pad sentinel
  }
  okk[tid] = karr[b * 512 + tid];

  const int qloc = wave * 16 + fr;
  const int qc = qloc + 511;             // pad slot (ok=0xFFFF) -> idx<0 -> clamp 0 -> -1e30
  const u16* Qb = Qr + ((size_t)bh * 500 + min(q0 + qloc, 499)) * 64;
  bf16x8 qf0 = *(const bf16x8*)(Qb + fo * 8);
  bf16x8 qf1 = *(const bf16x8*)(Qb + 32 + fo * 8);

  f32x4 o[4];
#pragma unroll
  for (int nf = 0; nf < 4; ++nf)
#pragma unroll
    for (int j = 0; j < 4; ++j) o[nf][j] = 0.f;
  float mrun = -1e30f, lrun = 0.f;

  const u16* Kb = Ktg + (size_t)bh * 32768;
  const u16* Vb = Vtg + (size_t)bh * 32768;
  const int sw = (fr & 7) << 4;
  const float SC = 0.18033688f;          // 0.125 * log2(e)
  const int lane = tid & 63;
  const int s0 = (lane & 15) | (((lane >> 4) & 1) << 5);   // P-exchange src lanes
  const int s1 = s0 + 16;
  const bool hi = (fo & 2) != 0;

  if (nt > 0) {
    async16(&Ks[0][tid * 8], Kb + tid * 8);
    async16(&Vs[0][tid * 8], Vb + tid * 8);
  }
  __syncthreads();

  for (int t = 0; t < nt; ++t) {
    const int cur = t & 1;
    if (t + 1 < nt) {
      async16(&Ks[cur ^ 1][tid * 8], Kb + (t + 1) * 4096 + tid * 8);
      async16(&Vs[cur ^ 1][tid * 8], Vb + (t + 1) * 4096 + tid * 8);
    }
    const char* Kt = (const char*)(cur ? &Ks[1][0] : &Ks[0][0]);
    const char* Vt = (const char*)(cur ? &Vs[1][0] : &Vs[0][0]);

    f32x4 sacc[4];
    __builtin_amdgcn_s_setprio(1);
#pragma unroll
    for (int nf = 0; nf < 4; ++nf) {
#pragma unroll
      for (int jj = 0; jj < 4; ++jj) sacc[nf][jj] = 0.f;
      int rb = (nf * 16 + fr) * 128;
      bf16x8 kb0 = *(const bf16x8*)(Kt + rb + ((fo * 16) ^ sw));
      bf16x8 kb1 = *(const bf16x8*)(Kt + rb + ((64 + fo * 16) ^ sw));
      sacc[nf] = __builtin_amdgcn_mfma_f32_16x16x32_bf16(kb0, qf0, sacc[nf], 0, 0, 0);
      sacc[nf] = __builtin_amdgcn_mfma_f32_16x16x32_bf16(kb1, qf1, sacc[nf], 0, 0, 0);
    }
    __builtin_amdgcn_s_setprio(0);

    float p2[4][4];
    float pmax = -3e30f;
#pragma unroll
    for (int nf = 0; nf < 4; ++nf) {
      u16x4 ok4 = *(const u16x4*)&okk[t * 64 + nf * 16 + fo * 4];
#pragma unroll
      for (int r = 0; r < 4; ++r) {
        int idx2 = max(qc - (int)ok4[r], 0);
        float s2 = fmaf(sacc[nf][r], SC, rel2[idx2]);
        p2[nf][r] = s2;
        pmax = fmaxf(pmax, s2);
      }
    }
    pmax = fmaxf(pmax, __shfl_xor(pmax, 16, 64));
    pmax = fmaxf(pmax, __shfl_xor(pmax, 32, 64));

    if (!__all(pmax <= mrun + 8.0f)) {   // defer-max (T13)
      float mnew = fmaxf(mrun, pmax);
      float scl = EXP2(mrun - mnew);
      lrun *= scl;
#pragma unroll
      for (int nf = 0; nf < 4; ++nf)
#pragma unroll
        for (int r = 0; r < 4; ++r) o[nf][r] *= scl;
      mrun = mnew;
    }

    float lsum = 0.f;
    u32 Wx[4], Wy[4];                    // cvtpk'd P words per nf (static indexing)
#pragma unroll
    for (int nf = 0; nf < 4; ++nf) {
      float e0 = EXP2(p2[nf][0] - mrun);
      float e1 = EXP2(p2[nf][1] - mrun);
      float e2 = EXP2(p2[nf][2] - mrun);
      float e3 = EXP2(p2[nf][3] - mrun);
      lsum += (e0 + e1) + (e2 + e3);
      Wx[nf] = cvtpk(e0, e1);
      Wy[nf] = cvtpk(e2, e3);
    }
    lsum += __shfl_xor(lsum, 16, 64);
    lsum += __shfl_xor(lsum, 32, 64);
    lrun += lsum;

    // in-register P redistribution: pa0 from nf=fo>>1, pa1 from nf=2+(fo>>1)
    u32 a0x0 = (u32)__shfl((int)Wx[0], s0, 64), b0x0 = (u32)__shfl((int)Wx[1], s0, 64);
    u32 a0y0 = (u32)__shfl((int)Wy[0], s0, 64), b0y0 = (u32)__shfl((int)Wy[1], s0, 64);
    u32 a0x1 = (u32)__shfl((int)Wx[0], s1, 64), b0x1 = (u32)__shfl((int)Wx[1], s1, 64);
    u32 a0y1 = (u32)__shfl((int)Wy[0], s1, 64), b0y1 = (u32)__shfl((int)Wy[1], s1, 64);
    u32 a1x0 = (u32)__shfl((int)Wx[2], s0, 64), b1x0 = (u32)__shfl((int)Wx[3], s0, 64);
    u32 a1y0 = (u32)__shfl((int)Wy[2], s0, 64), b1y0 = (u32)__shfl((int)Wy[3], s0, 64);
    u32 a1x1 = (u32)__shfl((int)Wx[2], s1, 64), b1x1 = (u32)__shfl((int)Wx[3], s1, 64);
    u32 a1y1 = (u32)__shfl((int)Wy[2], s1, 64), b1y1 = (u32)__shfl((int)Wy[3], s1, 64);
    uint4 pa0u, pa1u;
    pa0u.x = hi ? b0x0 : a0x0;  pa0u.y = hi ? b0y0 : a0y0;
    pa0u.z = hi ? b0x1 : a0x1;  pa0u.w = hi ? b0y1 : a0y1;
    pa1u.x = hi ? b1x0 : a1x0;  pa1u.y = hi ? b1y0 : a1y0;
    pa1u.z = hi ? b1x1 : a1x1;  pa1u.w = hi ? b1y1 : a1y1;
    bf16x8 pa0 = *(bf16x8*)&pa0u;
    bf16x8 pa1 = *(bf16x8*)&pa1u;

    __builtin_amdgcn_s_setprio(1);
#pragma unroll
    for (int nf = 0; nf < 4; ++nf) {
      int rb = (nf * 16 + fr) * 128;
      bf16x8 vb0 = *(const bf16x8*)(Vt + rb + ((fo * 16) ^ sw));
      bf16x8 vb1 = *(const bf16x8*)(Vt + rb + ((64 + fo * 16) ^ sw));
      o[nf] = __builtin_amdgcn_mfma_f32_16x16x32_bf16(vb0, pa0, o[nf], 0, 0, 0);
      o[nf] = __builtin_amdgcn_mfma_f32_16x16x32_bf16(vb1, pa1, o[nf], 0, 0, 0);
    }
    __builtin_amdgcn_s_setprio(0);
    __syncthreads();
  }

  // epilogue: normalize+clip, bounce through (now dead) Ks for coalesced stores
  float inv = (lrun > 0.f) ? 1.f / lrun : 0.f;
  char* Pw = (char*)&Ks[0][0] + wave * 2048;          // 2KB per wave (16KB total, fits Ks)
#pragma unroll
  for (int nf = 0; nf < 4; ++nf) {
    float v0 = fminf(fmaxf(o[nf][0] * inv, -30.f), 30.f);
    float v1 = fminf(fmaxf(o[nf][1] * inv, -30.f), 30.f);
    float v2 = fminf(fmaxf(o[nf][2] * inv, -30.f), 30.f);
    float v3 = fminf(fmaxf(o[nf][3] * inv, -30.f), 30.f);
    uint2 w; w.x = cvtpk(v0, v1); w.y = cvtpk(v2, v3);
    *(uint2*)(Pw + fr * 128 + ((nf * 32 + fo * 8) ^ sw)) = w;
  }
  {
    int ro = lane >> 2, c = lane & 3;
    int swr = (ro & 7) << 4;
    bf16x8 v0 = *(const bf16x8*)(Pw + ro * 128 + ((c * 32) ^ swr));
    bf16x8 v1 = *(const bf16x8*)(Pw + ro * 128 + ((c * 32 + 16) ^ swr));
    int token = q0 + wave * 16 + ro;
    if (token < 500) {
      u16* dst = AO + (size_t)(b * 500 + token) * 1024 + h * 64 + c * 16;
      *(bf16x8*)dst = v0;
      *(bf16x8*)(dst + 8) = v1;
    }
  }
}

// ---------------- launch ----------------
extern "C" void kernel_launch(void* const* d_in, const int* in_sizes, int n_in,
                              void* d_out, int out_size, void* d_ws, size_t ws_size,
                              hipStream_t stream) {
  const float* query = (const float*)d_in[0];
  const float* key_  = (const float*)d_in[1];
  const float* value = (const float*)d_in[2];
  const void*  mask  = d_in[3];
  const float* Wq = (const float*)d_in[4];
  const float* bq = (const float*)d_in[5];
  const float* Wk = (const float*)d_in[6];
  const float* bk = (const float*)d_in[7];
  const float* Wv = (const float*)d_in[8];
  const float* bv = (const float*)d_in[9];
  const float* Wo = (const float*)d_in[10];
  const float* bo = (const float*)d_in[11];
  const float* rel = (const float*)d_in[12];

  // ws map: Wb 8.39MB | 5 slots x 32MiB | misc ~0.26MB
  // A: Xq | B: XkC -> AO | C: XvC | D: Ktg | E: Vtg
  // Qro lives in d_out (f32 65.5MB >= 32.8MB bf16 scratch; overwritten by out-proj).
  char* ws = (char*)d_ws;
  const size_t SLOT = 33554432;
  u16* Wb = (u16*)ws;
  char* Aq = ws + 8388608;
  char* Bq = Aq + SLOT;
  char* Cq = Bq + SLOT;
  char* Dq = Cq + SLOT;
  char* Eq = Dq + SLOT;
  char* MISC = Eq + SLOT;
  u16* karr  = (u16*)(MISC + 65536);
  int* kept  = (int*)(MISC + 131072);
  float* tab = (float*)(MISC + 131584);
  u16* Qro = (u16*)d_out;

  build_gather<<<32, 512, 0, stream>>>(mask, karr, kept);

  // one launch: W cvt x4 | Q cvt | K/V gather-cvt | rope table
  prep<<<36543, 256, 0, stream>>>(Wq, Wk, Wv, Wo, Wb,
                                  query, (u16*)Aq,
                                  key_, value, karr, kept, (u16*)Bq, (u16*)Cq,
                                  tab);

  // fused Q+K+V projections; K/V epilogues emit swizzled Ktg/Vtg tiles directly
  gemm_fused<<<1528, 512, 0, stream>>>((u16*)Aq, (u16*)Bq, (u16*)Cq, Wb,
                                       bq, bk, bv,
                                       Qro, (u16*)Dq, (u16*)Eq, tab, karr, kept);

  attn_kernel<<<2048, 512, 0, stream>>>(Qro, (u16*)Dq, (u16*)Eq, rel,
                                        karr, kept, (u16*)Bq);                  // AO=B

  gemm_out<<<504, 512, 0, stream>>>((u16*)Bq, Wb + 3 * 1048576, bo, (float*)d_out);
}

// Round 23
// 245.650 us; speedup vs baseline: 1.0248x; 1.0248x over previous
//
#include <hip/hip_runtime.h>
#include <math.h>

// FlashMultiHeadAttention: B=32 S=500 H=1024 NH=16 HD=64, rope + rel-pos-bias + key-pad mask.
// Pipeline: [gather-list scan w/ inline mask-mode detect]
//           [PREP: W cvt x4 + Q cvt + K/V gather-cvt + rope table, ONE launch]
//           [FUSED proj GEMM: Q(full, rope+transpose) + K(compact -> roped swizzled Ktg tiles)
//            + V(compact -> transposed swizzled Vtg tiles), ONE launch]
//           [flash attn] [out proj GEMM]
// GEMM core: 256x128 tile, BK=32, 2 LDS buffers (48KB -> 3 blocks/CU co-resident),
// row-pair packed 128B LDS rows + XOR slot swizzle, T3-minimum single-barrier loop.

typedef unsigned short u16;
typedef unsigned int   u32;
typedef unsigned char  u8;
using bf16x8 = __attribute__((ext_vector_type(8))) short;
using f32x4  = __attribute__((ext_vector_type(4))) float;
using f32x2  = __attribute__((ext_vector_type(2))) float;
using u16x4  = __attribute__((ext_vector_type(4))) unsigned short;

#define DEV __device__ __forceinline__

#if __has_builtin(__builtin_amdgcn_exp2f)
#define EXP2(x) __builtin_amdgcn_exp2f(x)
#else
#define EXP2(x) exp2f(x)
#endif

DEV u16 f2bf(float f) {                 // RNE f32 -> bf16
  union { float f; u32 u; } c; c.f = f;
  u32 u = c.u;
  return (u16)((u + 0x7FFFu + ((u >> 16) & 1u)) >> 16);
}
DEV float bf2f(u16 h) {
  union { u32 u; float f; } c; c.u = ((u32)h) << 16;
  return c.f;
}
DEV u32 cvtpk(float a, float b) {       // packed pair via HW cvt (T12)
  u32 r;
  asm("v_cvt_pk_bf16_f32 %0, %1, %2" : "=v"(r) : "v"(a), "v"(b));
  return r;
}

// async global->LDS, 16B/lane; LDS dest = wave-uniform base + lane*16 (linear).
DEV void async16(void* l, const void* g) {
  __builtin_amdgcn_global_load_lds(
      (__attribute__((address_space(1))) unsigned int*)g,
      (__attribute__((address_space(3))) unsigned int*)l, 16, 0, 0);
}

// ---------------- gather list + inline mask-mode detection ----------------
__global__ __launch_bounds__(512) void build_gather(const void* __restrict__ mraw,
                                                    u16* __restrict__ karr,
                                                    int* __restrict__ kept) {
  const int b = blockIdx.x;
  const int t = threadIdx.x;
  const int lane = t & 63, wave = t >> 6;
  __shared__ int s_li, s_lf;
  __shared__ int wbase[8];
  __shared__ int wpop[8];
  if (t == 0) { s_li = 0; s_lf = 0; }
  __syncthreads();
  const u32* w = (const u32*)mraw;
  int li = 0, lf = 0;
  for (int g = t; g < 4000; g += 512) {      // same 4000 words in every block -> same mode
    u32 v = w[g];
    li |= !(v == 0u || v == 1u);
    lf |= !(v == 0u || v == 0x3F800000u);
  }
  if (li) atomicOr(&s_li, 1);
  if (lf) atomicOr(&s_lf, 1);
  __syncthreads();
  const int mode = (!s_li) ? 0 : ((!s_lf) ? 1 : 2);   // 0=int32, 1=float32, 2=uint8
  int v = 0;
  if (t < 500) {
    if (mode == 0)      v = ((const int*)mraw)[b * 500 + t] != 0;
    else if (mode == 1) v = (((const float*)mraw)[b * 500 + t] != 0.0f);
    else                v = ((const u8*)mraw)[b * 500 + t] != 0;
  }
  unsigned long long bal = __ballot(v != 0);
  karr[b * 512 + t] = 0xFFFF;
  if (lane == 0) wpop[wave] = __popcll(bal);
  __syncthreads();
  if (t == 0) {
    int s = 0;
    for (int ww = 0; ww < 8; ++ww) { wbase[ww] = s; s += wpop[ww]; }
    kept[b] = s;
  }
  __syncthreads();
  if (v) {
    int rank = wbase[wave] + __popcll(bal & ((1ull << lane) - 1ull));
    karr[b * 512 + rank] = (u16)t;
  }
}

// ---------------- PREP: W cvt x4 | Q cvt | K/V gather-cvt | rope table (one launch) ----------
// grid 36543 = 4096 (W) + 16000 (Q) + 16384 (K/V gather) + 63 (rope table)
__global__ __launch_bounds__(256) void prep(
    const float* __restrict__ Wq, const float* __restrict__ Wk,
    const float* __restrict__ Wv, const float* __restrict__ Wo,
    u16* __restrict__ Wb,
    const float* __restrict__ query, u16* __restrict__ Xq,
    const float* __restrict__ key_, const float* __restrict__ value,
    const u16* __restrict__ karr, const int* __restrict__ kept,
    u16* __restrict__ XkC, u16* __restrict__ XvC,
    float* __restrict__ tab) {
  const int bid = blockIdx.x;
  const int tid = threadIdx.x;
  if (bid < 4096) {
    const int wsel = bid >> 10;
    const float* src = (wsel == 0) ? Wq : (wsel == 1) ? Wk : (wsel == 2) ? Wv : Wo;
    int i = (bid & 1023) * 256 + tid;
    f32x4 f = *(const f32x4*)(src + (size_t)i * 4);
    u16x4 o;
    o[0] = f2bf(f[0]); o[1] = f2bf(f[1]); o[2] = f2bf(f[2]); o[3] = f2bf(f[3]);
    *(u16x4*)(Wb + (size_t)wsel * 1048576 + (size_t)i * 4) = o;
  } else if (bid < 20096) {
    int i = (bid - 4096) * 256 + tid;
    f32x4 f = *(const f32x4*)(query + (size_t)i * 4);
    u16x4 o;
    o[0] = f2bf(f[0]); o[1] = f2bf(f[1]); o[2] = f2bf(f[2]); o[3] = f2bf(f[3]);
    *(u16x4*)(Xq + (size_t)i * 4) = o;
  } else if (bid < 36480) {
    const int local = bid - 20096;
    const int z = local >> 13;                       // 0 = K, 1 = V
    const int rem = local & 8191;
    const int b = rem >> 8;
    const int r = (rem & 255) * 2 + (tid >> 7);
    if (r >= kept[b]) return;
    const float* src = z ? value : key_;
    u16* dst = z ? XvC : XkC;
    const int c = (tid & 127) * 8;
    const int tok = karr[b * 512 + r];
    const float* s = src + ((size_t)b * 500 + tok) * 1024 + c;
    f32x4 f0 = *(const f32x4*)s;
    f32x4 f1 = *(const f32x4*)(s + 4);
    u16 o[8];
    o[0] = f2bf(f0[0]); o[1] = f2bf(f0[1]); o[2] = f2bf(f0[2]); o[3] = f2bf(f0[3]);
    o[4] = f2bf(f1[0]); o[5] = f2bf(f1[1]); o[6] = f2bf(f1[2]); o[7] = f2bf(f1[3]);
    *(bf16x8*)(dst + ((size_t)b * 512 + r) * 1024 + c) = *(bf16x8*)o;
  } else {
    int idx = (bid - 36480) * 256 + tid;
    if (idx >= 16000) return;
    int s = idx >> 5, j = idx & 31;
    float ang = (float)s * exp2f(-(float)j * 0.41524100f);  // 10000^(-j/32)
    float sn, cs;
    sincosf(ang, &sn, &cs);
    tab[idx * 2] = cs;
    tab[idx * 2 + 1] = sn;
  }
}

// ---------------- shared GEMM core (round-14 proven) ----------------
// 256x128 tile, BK=32, 512 thr / 8 waves (4Mx2N), per-wave 64x64 (4x4 frags).
// 2 LDS buffers (A 16KB + B 8KB each). Row-pair packed 128B rows, XOR slot swizzle.
// T3-minimum loop: STAGE(t+1,buf^1) -> ds_read -> lgkm(0) -> 16 MFMA -> vmcnt(0) -> barrier.
DEV void gemm_core(const u16* __restrict__ A, size_t abase,
                   const u16* __restrict__ W,
                   int m0, int n0, int Mloc,
                   u16* AS, u16* BS, f32x4 (&acc)[4][4], int tid) {
  const int wave = tid >> 6;
  const int wr = wave >> 1, wc = wave & 1;            // 4M x 2N
  const int fr = tid & 15, fo = (tid >> 4) & 3;
  const int fr2 = fr >> 1;
  const int aslot = ((4 * (fr & 1) + fo) ^ fr2) * 8;  // u16 offset within 64-u16 LDS row
  const int ATILE = 128 * 64;                         // 16KB
  const int BTILE = 64 * 64;                          // 8KB

#pragma unroll
  for (int mi = 0; mi < 4; ++mi)
#pragma unroll
    for (int ni = 0; ni < 4; ++ni)
#pragma unroll
      for (int j = 0; j < 4; ++j) acc[mi][ni][j] = 0.f;

  auto STG = [&](int t, int buf) {
    u16* sA = &AS[buf * ATILE];
    u16* sB = &BS[buf * BTILE];
#pragma unroll
    for (int i = 0; i < 2; ++i) {                     // A: 1024 chunks
      int c = i * 512 + tid;
      int r = c >> 3, v = (c & 7) ^ (r & 7);
      int ar = min(m0 + 2 * r + (v >> 2), Mloc - 1);
      async16(&sA[c * 8], A + abase + (size_t)ar * 1024 + t * 32 + (v & 3) * 8);
    }
    {                                                 // B: 512 chunks
      int c = tid;
      int r = c >> 3, v = (c & 7) ^ (r & 7);
      int nr = n0 + 2 * r + (v >> 2);
      async16(&sB[c * 8], W + (size_t)nr * 1024 + t * 32 + (v & 3) * 8);
    }
  };

  STG(0, 0);
  asm volatile("s_waitcnt vmcnt(0)" ::: "memory");
  __builtin_amdgcn_sched_barrier(0);
  __builtin_amdgcn_s_barrier();

  int cur = 0;
  for (int t = 0; t < 32; ++t) {
    if (t + 1 < 32) STG(t + 1, cur ^ 1);
    const u16* a0 = &AS[cur * ATILE];
    const u16* b0 = &BS[cur * BTILE];
    bf16x8 a[4], b[4];
#pragma unroll
    for (int mi = 0; mi < 4; ++mi)
      a[mi] = *(const bf16x8*)&a0[(wr * 32 + mi * 8 + fr2) * 64 + aslot];
#pragma unroll
    for (int ni = 0; ni < 4; ++ni)
      b[ni] = *(const bf16x8*)&b0[(wc * 32 + ni * 8 + fr2) * 64 + aslot];
    asm volatile("s_waitcnt lgkmcnt(0)" ::: "memory");
    __builtin_amdgcn_sched_barrier(0);
    __builtin_amdgcn_s_setprio(1);
#pragma unroll
    for (int mi = 0; mi < 4; ++mi)
#pragma unroll
      for (int ni = 0; ni < 4; ++ni)
        acc[mi][ni] = __builtin_amdgcn_mfma_f32_16x16x32_bf16(a[mi], b[ni], acc[mi][ni], 0, 0, 0);
    __builtin_amdgcn_s_setprio(0);
    asm volatile("s_waitcnt vmcnt(0)" ::: "memory");
    __builtin_amdgcn_sched_barrier(0);
    __builtin_amdgcn_s_barrier();
    cur ^= 1;
  }
  __syncthreads();
}

// ---------------- FUSED projection GEMM ----------------
// grid 1528 = 504 (Q full: rope+transpose -> Qro) + 512 (K compact: rope -> swizzled Ktg
// tiles) + 512 (V compact: transpose -> swizzled Vtg tiles).
__global__ __launch_bounds__(512, 4) void gemm_fused(
    const u16* __restrict__ Xq, const u16* __restrict__ XkC, const u16* __restrict__ XvC,
    const u16* __restrict__ Wb,
    const float* __restrict__ bq, const float* __restrict__ bk, const float* __restrict__ bv,
    u16* __restrict__ Qro, u16* __restrict__ Ktg, u16* __restrict__ Vtg,
    const float* __restrict__ tabg, const u16* __restrict__ karr,
    const int* __restrict__ keptp) {
  __shared__ __attribute__((aligned(16))) u16 SH[2 * 128 * 64 + 2 * 64 * 64];  // 48KB
  u16* AS = &SH[0];
  u16* BS = &SH[2 * 128 * 64];
  const int bid = blockIdx.x;
  const int tid = threadIdx.x;
  const int wave = tid >> 6;
  const int wr = wave >> 1, wc = wave & 1;
  const int fr = tid & 15, fo = (tid >> 4) & 3;
  const int lane = tid & 63;

  f32x4 acc[4][4];

  if (bid < 504) {
    // ---- Q path: full M=16000, rope+transpose epilogue -> Qro [bh][s][64] ----
    const int swz = (bid & 7) * 63 + (bid >> 3);
    const int m0 = (swz >> 3) * 256;
    const int n0 = (swz & 7) * 128;
    gemm_core(Xq, 0, Wb, m0, n0, 16000, AS, BS, acc, tid);

    float* fw = (float*)&SH[0] + wave * 1024;         // 4KB per wave (disjoint regions)
    const int hh = (n0 >> 6) + wc;
    const int row = lane >> 2;
    const int jb = (lane & 3) * 8;
    float bvv[4];
#pragma unroll
    for (int ni = 0; ni < 4; ++ni) bvv[ni] = bq[n0 + wc * 64 + ni * 16 + fr];
#pragma unroll
    for (int mi = 0; mi < 4; ++mi) {
#pragma unroll
      for (int ni = 0; ni < 4; ++ni)
#pragma unroll
        for (int r = 0; r < 4; ++r)
          fw[(fo * 4 + r) * 64 + ni * 16 + fr] = acc[mi][ni][r] + bvv[ni];
      int m = m0 + wr * 64 + mi * 16 + row;
      if (m < 16000) {
        int bb = (u32)m / 500u;
        int ss = m - bb * 500;
        u16* dst = Qro + (((size_t)(bb * 16 + hh)) * 500 + ss) * 64;
        bf16x8 va, vb;
#pragma unroll
        for (int p = 0; p < 8; ++p) {
          int j = jb + p;
          float x0 = fw[row * 64 + j];
          float x1 = fw[row * 64 + 32 + j];
          float xe = fw[row * 64 + 2 * j];
          float xo = fw[row * 64 + 2 * j + 1];
          f32x2 cn = *(const f32x2*)(tabg + (ss * 32 + j) * 2);
          va[p] = (short)f2bf(x0 * cn[0] - xo * cn[1]);
          vb[p] = (short)f2bf(x1 * cn[0] + xe * cn[1]);
        }
        *(bf16x8*)(dst + jb) = va;
        *(bf16x8*)(dst + 32 + jb) = vb;
      }
      __builtin_amdgcn_s_waitcnt(0);                  // lgkm: fw reads done before overwrite
    }
  } else {
    // ---- K/V compact paths ----
    const bool isV = (bid >= 1016);
    const int local = isV ? (bid - 1016) : (bid - 504);
    const u16* A = isV ? XvC : XkC;
    const u16* W = Wb + (isV ? 2 : 1) * 1048576;
    const float* bias = isV ? bv : bk;
    const int swz = (local & 7) * 64 + (local >> 3);  // bijective: 512 = 8*64
    const int mb = swz >> 3;
    const int n0 = (swz & 7) * 128;
    const int b = mb >> 1, rb = mb & 1;
    const int kb = keptp[b];
    if (rb * 256 >= kb) return;
    const int m0 = rb * 256;
    gemm_core(A, (size_t)b * 512 * 1024, W, m0, n0, kb, AS, BS, acc, tid);

    // f32 bounce with stride-66 rows (conflict-free strided column reads for V)
    float* fw = (float*)&SH[0] + wave * 1056;         // 16 x 66 f32 per wave (disjoint)
    const int hh = (n0 >> 6) + wc;
    float bvv[4];
#pragma unroll
    for (int ni = 0; ni < 4; ++ni) bvv[ni] = bias[n0 + wc * 64 + ni * 16 + fr];

    if (!isV) {
      // K: rope per rank, write pre-swizzled Ktg tiles [bh][tile][rin][128B]
      const int row = lane >> 2;
      const int jb = (lane & 3) * 8;
#pragma unroll
      for (int mi = 0; mi < 4; ++mi) {
#pragma unroll
        for (int ni = 0; ni < 4; ++ni)
#pragma unroll
          for (int r = 0; r < 4; ++r)
            fw[(fo * 4 + r) * 66 + ni * 16 + fr] = acc[mi][ni][r] + bvv[ni];
        int rk = m0 + wr * 64 + mi * 16 + row;
        int tile = rk >> 6, rin = rk & 63;
        int swk = (rin & 7) << 4;
        if (tile * 64 < kb) {
          char* outp = (char*)(Ktg + (((size_t)(b * 16 + hh)) * 8 + tile) * 4096) + rin * 128;
          bf16x8 va, vb;
          if (rk < kb) {
            int tok = karr[b * 512 + rk];
#pragma unroll
            for (int p = 0; p < 8; ++p) {
              int j = jb + p;
              float x0 = fw[row * 66 + j];
              float x1 = fw[row * 66 + 32 + j];
              float xe = fw[row * 66 + 2 * j];
              float xo = fw[row * 66 + 2 * j + 1];
              f32x2 cn = *(const f32x2*)(tabg + (tok * 32 + j) * 2);
              va[p] = (short)f2bf(x0 * cn[0] - xo * cn[1]);
              vb[p] = (short)f2bf(x1 * cn[0] + xe * cn[1]);
            }
          } else {
#pragma unroll
            for (int p = 0; p < 8; ++p) { va[p] = 0; vb[p] = 0; }
          }
          *(bf16x8*)(outp + ((2 * jb) ^ swk)) = va;
          *(bf16x8*)(outp + ((64 + 2 * jb) ^ swk)) = vb;
        }
        __builtin_amdgcn_s_waitcnt(0);                // lgkm: fw reads done before overwrite
      }
    } else {
      // V: transpose in bounce (lane = d), write pre-swizzled Vtg tiles [bh][tile][d][128B]
      const int d = lane;
      const int swv = (d & 7) << 4;
#pragma unroll
      for (int mi = 0; mi < 4; ++mi) {
#pragma unroll
        for (int ni = 0; ni < 4; ++ni)
#pragma unroll
          for (int r = 0; r < 4; ++r)
            fw[(fo * 4 + r) * 66 + ni * 16 + fr] = acc[mi][ni][r] + bvv[ni];
        int rk0 = m0 + wr * 64 + mi * 16;
        int tile = rk0 >> 6, rin0 = rk0 & 63;
        if (tile * 64 < kb) {
          char* rowp = (char*)(Vtg + (((size_t)(b * 16 + hh)) * 8 + tile) * 4096) + d * 128;
          bf16x8 va, vb;
#pragma unroll
          for (int t2 = 0; t2 < 8; ++t2)
            va[t2] = (rk0 + t2 < kb) ? (short)f2bf(fw[t2 * 66 + d]) : (short)0;
#pragma unroll
          for (int t2 = 0; t2 < 8; ++t2)
            vb[t2] = (rk0 + 8 + t2 < kb) ? (short)f2bf(fw[(8 + t2) * 66 + d]) : (short)0;
          *(bf16x8*)(rowp + ((2 * rin0) ^ swv)) = va;
          *(bf16x8*)(rowp + ((2 * rin0 + 16) ^ swv)) = vb;
        }
        __builtin_amdgcn_s_waitcnt(0);                // lgkm: fw reads done before overwrite
      }
    }
  }
}

// ---------------- out-projection GEMM: full, f32 out ----------------
__global__ __launch_bounds__(512, 4) void gemm_out(const u16* __restrict__ A,
                                                   const u16* __restrict__ W,
                                                   const float* __restrict__ bias,
                                                   float* __restrict__ Cout) {
  __shared__ __attribute__((aligned(16))) u16 SH[2 * 128 * 64 + 2 * 64 * 64];
  u16* AS = &SH[0];
  u16* BS = &SH[2 * 128 * 64];
  const int bid = blockIdx.x;
  const int tid = threadIdx.x;
  const int wave = tid >> 6;
  const int wr = wave >> 1, wc = wave & 1;
  const int fr = tid & 15, fo = (tid >> 4) & 3;
  const int swz = (bid & 7) * 63 + (bid >> 3);
  const int m0 = (swz >> 3) * 256;
  const int n0 = (swz & 7) * 128;

  f32x4 acc[4][4];
  gemm_core(A, 0, W, m0, n0, 16000, AS, BS, acc, tid);

  float* fw = (float*)&SH[0] + wave * 1024;           // 4KB per wave (disjoint regions)
#pragma unroll
  for (int mi = 0; mi < 4; ++mi) {
#pragma unroll
    for (int ni = 0; ni < 4; ++ni) {
      float bv = bias[n0 + wc * 64 + ni * 16 + fr];
#pragma unroll
      for (int r = 0; r < 4; ++r)
        fw[(fo * 4 + r) * 64 + ni * 16 + fr] = acc[mi][ni][r] + bv;
    }
    int lane = tid & 63;
    int ro = lane >> 2, ch = lane & 3;
    int m = m0 + wr * 64 + mi * 16 + ro;
    f32x4 v0 = *(const f32x4*)&fw[ro * 64 + ch * 16];
    f32x4 v1 = *(const f32x4*)&fw[ro * 64 + ch * 16 + 4];
    f32x4 v2 = *(const f32x4*)&fw[ro * 64 + ch * 16 + 8];
    f32x4 v3 = *(const f32x4*)&fw[ro * 64 + ch * 16 + 12];
    if (m < 16000) {
      float* dst = Cout + (size_t)m * 1024 + n0 + wc * 64 + ch * 16;
      *(f32x4*)dst = v0;
      *(f32x4*)(dst + 4) = v1;
      *(f32x4*)(dst + 8) = v2;
      *(f32x4*)(dst + 12) = v3;
    }
    __builtin_amdgcn_s_waitcnt(0);                    // lgkm: fw reads done before overwrite
  }
}

// ---------------- flash attention: compressed k, swapped QK^T, in-reg softmax ----------------
__global__ __launch_bounds__(512) void attn_kernel(const u16* __restrict__ Qr,
                                                   const u16* __restrict__ Ktg,
                                                   const u16* __restrict__ Vtg,
                                                   const float* __restrict__ rel_emb,
                                                   const u16* __restrict__ karr,
                                                   const int* __restrict__ kept,
                                                   u16* __restrict__ AO) {
  const int bid = blockIdx.x;
  const int bh = ((bid >> 5) << 3) | (bid & 7);
  const int qb = (bid >> 3) & 3;
  const int h = bh & 15, b = bh >> 4;
  const int q0 = qb * 128;
  const int tid = threadIdx.x;
  const int wave = tid >> 6;
  const int fr = tid & 15, fo = (tid >> 4) & 3;

  __shared__ __attribute__((aligned(16))) u16 Ks[2][4096];
  __shared__ __attribute__((aligned(16))) u16 Vs[2][4096];
  __shared__ __attribute__((aligned(16))) u16 Pl[8][1024];
  __shared__ float rel2[640];
  __shared__ u16 okk[512];

  const int nt = (kept[b] + 63) >> 6;
  const float LOG2E = 1.44269504f;
  for (int i = tid; i < 640; i += 512) {
    int g = min(max(q0 - 12 + i, 0), 998);
    rel2[i] = (i == 0) ? -1e30f : rel_emb[g * 16 + h] * LOG2E;   // rel2[0] = pad sentinel
  }
  okk[tid] = karr[b * 512 + tid];

  const int qloc = wave * 16 + fr;
  const int qc = qloc + 511;             // pad slot (ok=0xFFFF) -> idx<0 -> clamp 0 -> -1e30
  const u16* Qb = Qr + ((size_t)bh * 500 + min(q0 + qloc, 499)) * 64;
  bf16x8 qf0 = *(const bf16x8*)(Qb + fo * 8);
  bf16x8 qf1 = *(const bf16x8*)(Qb + 32 + fo * 8);

  f32x4 o[4];
#pragma unroll
  for (int nf = 0; nf < 4; ++nf)
#pragma unroll
    for (int j = 0; j < 4; ++j) o[nf][j] = 0.f;
  float mrun = -1e30f, lrun = 0.f;

  const u16* Kb = Ktg + (size_t)bh * 32768;
  const u16* Vb = Vtg + (size_t)bh * 32768;
  const int sw = (fr & 7) << 4;
  const float SC = 0.18033688f;          // 0.125 * log2(e)

  if (nt > 0) {
    async16(&Ks[0][tid * 8], Kb + tid * 8);
    async16(&Vs[0][tid * 8], Vb + tid * 8);
  }
  __syncthreads();

  for (int t = 0; t < nt; ++t) {
    const int cur = t & 1;
    if (t + 1 < nt) {
      async16(&Ks[cur ^ 1][tid * 8], Kb + (t + 1) * 4096 + tid * 8);
      async16(&Vs[cur ^ 1][tid * 8], Vb + (t + 1) * 4096 + tid * 8);
    }
    const char* Kt = (const char*)(cur ? &Ks[1][0] : &Ks[0][0]);
    const char* Vt = (const char*)(cur ? &Vs[1][0] : &Vs[0][0]);

    f32x4 sacc[4];
    __builtin_amdgcn_s_setprio(1);
#pragma unroll
    for (int nf = 0; nf < 4; ++nf) {
#pragma unroll
      for (int jj = 0; jj < 4; ++jj) sacc[nf][jj] = 0.f;
      int rb = (nf * 16 + fr) * 128;
      bf16x8 kb0 = *(const bf16x8*)(Kt + rb + ((fo * 16) ^ sw));
      bf16x8 kb1 = *(const bf16x8*)(Kt + rb + ((64 + fo * 16) ^ sw));
      sacc[nf] = __builtin_amdgcn_mfma_f32_16x16x32_bf16(kb0, qf0, sacc[nf], 0, 0, 0);
      sacc[nf] = __builtin_amdgcn_mfma_f32_16x16x32_bf16(kb1, qf1, sacc[nf], 0, 0, 0);
    }
    __builtin_amdgcn_s_setprio(0);

    float p2[4][4];
    float pmax = -3e30f;
#pragma unroll
    for (int nf = 0; nf < 4; ++nf) {
      u16x4 ok4 = *(const u16x4*)&okk[t * 64 + nf * 16 + fo * 4];
#pragma unroll
      for (int r = 0; r < 4; ++r) {
        int idx2 = max(qc - (int)ok4[r], 0);
        float s2 = fmaf(sacc[nf][r], SC, rel2[idx2]);
        p2[nf][r] = s2;
        pmax = fmaxf(pmax, s2);
      }
    }
    pmax = fmaxf(pmax, __shfl_xor(pmax, 16, 64));
    pmax = fmaxf(pmax, __shfl_xor(pmax, 32, 64));

    if (!__all(pmax <= mrun + 8.0f)) {   // defer-max (T13)
      float mnew = fmaxf(mrun, pmax);
      float scl = EXP2(mrun - mnew);
      lrun *= scl;
#pragma unroll
      for (int nf = 0; nf < 4; ++nf)
#pragma unroll
        for (int r = 0; r < 4; ++r) o[nf][r] *= scl;
      mrun = mnew;
    }

    float lsum = 0.f;
#pragma unroll
    for (int nf = 0; nf < 4; ++nf) {
      float e0 = EXP2(p2[nf][0] - mrun);
      float e1 = EXP2(p2[nf][1] - mrun);
      float e2 = EXP2(p2[nf][2] - mrun);
      float e3 = EXP2(p2[nf][3] - mrun);
      lsum += (e0 + e1) + (e2 + e3);
      uint2 w; w.x = cvtpk(e0, e1); w.y = cvtpk(e2, e3);
      *(uint2*)((char*)&Pl[wave][0] + fr * 128 + ((nf * 32 + fo * 8) ^ sw)) = w;
    }
    lsum += __shfl_xor(lsum, 16, 64);
    lsum += __shfl_xor(lsum, 32, 64);
    lrun += lsum;

    bf16x8 pa0 = *(const bf16x8*)((char*)&Pl[wave][0] + fr * 128 + ((fo * 16) ^ sw));
    bf16x8 pa1 = *(const bf16x8*)((char*)&Pl[wave][0] + fr * 128 + ((64 + fo * 16) ^ sw));
    __builtin_amdgcn_s_setprio(1);
#pragma unroll
    for (int nf = 0; nf < 4; ++nf) {
      int rb = (nf * 16 + fr) * 128;
      bf16x8 vb0 = *(const bf16x8*)(Vt + rb + ((fo * 16) ^ sw));
      bf16x8 vb1 = *(const bf16x8*)(Vt + rb + ((64 + fo * 16) ^ sw));
      o[nf] = __builtin_amdgcn_mfma_f32_16x16x32_bf16(vb0, pa0, o[nf], 0, 0, 0);
      o[nf] = __builtin_amdgcn_mfma_f32_16x16x32_bf16(vb1, pa1, o[nf], 0, 0, 0);
    }
    __builtin_amdgcn_s_setprio(0);
    __syncthreads();
  }

  float inv = (lrun > 0.f) ? 1.f / lrun : 0.f;
#pragma unroll
  for (int nf = 0; nf < 4; ++nf) {
    float v0 = fminf(fmaxf(o[nf][0] * inv, -30.f), 30.f);
    float v1 = fminf(fmaxf(o[nf][1] * inv, -30.f), 30.f);
    float v2 = fminf(fmaxf(o[nf][2] * inv, -30.f), 30.f);
    float v3 = fminf(fmaxf(o[nf][3] * inv, -30.f), 30.f);
    uint2 w; w.x = cvtpk(v0, v1); w.y = cvtpk(v2, v3);
    *(uint2*)((char*)&Pl[wave][0] + fr * 128 + ((nf * 32 + fo * 8) ^ sw)) = w;
  }
  {
    int lane = tid & 63;
    int ro = lane >> 2, c = lane & 3;
    int swr = (ro & 7) << 4;
    const char* Pw = (const char*)&Pl[wave][0];
    bf16x8 v0 = *(const bf16x8*)(Pw + ro * 128 + ((c * 32) ^ swr));
    bf16x8 v1 = *(const bf16x8*)(Pw + ro * 128 + ((c * 32 + 16) ^ swr));
    int token = q0 + wave * 16 + ro;
    if (token < 500) {
      u16* dst = AO + (size_t)(b * 500 + token) * 1024 + h * 64 + c * 16;
      *(bf16x8*)dst = v0;
      *(bf16x8*)(dst + 8) = v1;
    }
  }
}

// ---------------- launch ----------------
extern "C" void kernel_launch(void* const* d_in, const int* in_sizes, int n_in,
                              void* d_out, int out_size, void* d_ws, size_t ws_size,
                              hipStream_t stream) {
  const float* query = (const float*)d_in[0];
  const float* key_  = (const float*)d_in[1];
  const float* value = (const float*)d_in[2];
  const void*  mask  = d_in[3];
  const float* Wq = (const float*)d_in[4];
  const float* bq = (const float*)d_in[5];
  const float* Wk = (const float*)d_in[6];
  const float* bk = (const float*)d_in[7];
  const float* Wv = (const float*)d_in[8];
  const float* bv = (const float*)d_in[9];
  const float* Wo = (const float*)d_in[10];
  const float* bo = (const float*)d_in[11];
  const float* rel = (const float*)d_in[12];

  // ws map: Wb 8.39MB | 5 slots x 32MiB | misc ~0.26MB
  // A: Xq | B: XkC -> AO | C: XvC | D: Ktg | E: Vtg
  // Qro lives in d_out (f32 65.5MB >= 32.8MB bf16 scratch; overwritten by out-proj).
  char* ws = (char*)d_ws;
  const size_t SLOT = 33554432;
  u16* Wb = (u16*)ws;
  char* Aq = ws + 8388608;
  char* Bq = Aq + SLOT;
  char* Cq = Bq + SLOT;
  char* Dq = Cq + SLOT;
  char* Eq = Dq + SLOT;
  char* MISC = Eq + SLOT;
  u16* karr  = (u16*)(MISC + 65536);
  int* kept  = (int*)(MISC + 131072);
  float* tab = (float*)(MISC + 131584);
  u16* Qro = (u16*)d_out;

  build_gather<<<32, 512, 0, stream>>>(mask, karr, kept);

  // one launch: W cvt x4 | Q cvt | K/V gather-cvt | rope table
  prep<<<36543, 256, 0, stream>>>(Wq, Wk, Wv, Wo, Wb,
                                  query, (u16*)Aq,
                                  key_, value, karr, kept, (u16*)Bq, (u16*)Cq,
                                  tab);

  // fused Q+K+V projections; K/V epilogues emit swizzled Ktg/Vtg tiles directly
  gemm_fused<<<1528, 512, 0, stream>>>((u16*)Aq, (u16*)Bq, (u16*)Cq, Wb,
                                       bq, bk, bv,
                                       Qro, (u16*)Dq, (u16*)Eq, tab, karr, kept);

  attn_kernel<<<2048, 512, 0, stream>>>(Qro, (u16*)Dq, (u16*)Eq, rel,
                                        karr, kept, (u16*)Bq);                  // AO=B

  gemm_out<<<504, 512, 0, stream>>>((u16*)Bq, Wb + 3 * 1048576, bo, (float*)d_out);
}